// Round 1
// baseline (2019.969 us; speedup 1.0000x reference)
//
#include <hip/hip_runtime.h>
#include <stdint.h>

// FlashFFTConvND == depthwise linear 2D conv (circular conv of 256-pad == linear
// conv since 128+64-1 <= 256):
//   y[b,c,i,j] = postgate * sum_{p<64,q<64} (u*pregate)[b,c,i-p,j-q] * k[c,p,q]
//
// R1 (this file): correct VALU direct conv, bf16 u_work staged in LDS with
// zero halo (rows via half-image window, cols via +64 left pad). One workgroup
// per (image, row-half). Expect ~1.2-1.7 ms, VALU-bound.
// R2 roadmap: same staging, inner loop -> mfma_f32_16x16x32_bf16 with K = absolute
// input rows, kernel as banded Toeplitz operand (skip all-zero 16x16x32 blocks).

typedef unsigned int uint32;

__device__ __forceinline__ unsigned short f2bf(float f) {
    uint32 x = __float_as_uint(f);
    // round-to-nearest-even bf16 (inputs are finite; no NaN handling needed)
    uint32 r = (x + 0x7fffu + ((x >> 16) & 1u)) >> 16;
    return (unsigned short)r;
}

__global__ __launch_bounds__(256, 2)
void conv_direct(const float* __restrict__ u, const float* __restrict__ kk,
                 const float* __restrict__ pregate, const float* __restrict__ postgate,
                 float* __restrict__ out)
{
    // uL rows [0,128) hold input rows [i0-63, i0+64]; cols [64,192) hold input
    // cols [0,128), cols [0,64) are zeros (left halo). Pitch 192*2B = 384B
    // (384 % 128 == 0 -> row starts 16B aligned; bank spread of the 16B reads
    // works out to exactly 8 accesses/bank = conflict-free minimum).
    __shared__ unsigned short uL[128][192];   // 48 KiB bf16
    __shared__ float kL[64][64];              // 16 KiB fp32

    const int bx  = blockIdx.x;
    const int img = bx >> 1;        // b*256 + c
    const int h   = bx & 1;
    const int i0  = h * 64;
    const int c   = img & 255;
    const int tid = threadIdx.x;

    const float* uimg = u        + (size_t)img * (128*128);
    const float* pimg = pregate  + (size_t)img * (128*128);
    const float* gimg = postgate + (size_t)img * (128*128);
    float*       oimg = out      + (size_t)img * (128*128);
    const float* kimg = kk       + (size_t)c   * (64*64);

    // ---- stage: zero left halo (cols [0,64) of every row) ----
    {
        uint4 z = make_uint4(0u, 0u, 0u, 0u);
        for (int it = tid; it < 128*8; it += 256) {        // 8 x 16B per row
            int row = it >> 3, c16 = it & 7;
            ((uint4*)&uL[row][0])[c16] = z;
        }
    }
    // ---- stage: k (fp32, keeps precision; broadcast reads later) ----
    {
        const float4* ksrc = (const float4*)kimg;
        float4*       kdst = (float4*)&kL[0][0];
        for (int it = tid; it < 64*64/4; it += 256) kdst[it] = ksrc[it];
    }
    // ---- stage: u*pregate -> bf16, rows ir = Lr + i0 - 63 (zeros outside) ----
    {
        for (int it = tid; it < 128*32; it += 256) {
            int Lr = it >> 5, c4 = (it & 31) * 4;
            int ir = Lr + i0 - 63;
            float4 v = make_float4(0.f, 0.f, 0.f, 0.f);
            if (ir >= 0 && ir < 128) {
                float4 a = *(const float4*)(uimg + ir*128 + c4);
                float4 p = *(const float4*)(pimg + ir*128 + c4);
                v.x = a.x*p.x; v.y = a.y*p.y; v.z = a.z*p.z; v.w = a.w*p.w;
            }
            uint2 packed;
            packed.x = (uint32)f2bf(v.x) | ((uint32)f2bf(v.y) << 16);
            packed.y = (uint32)f2bf(v.z) | ((uint32)f2bf(v.w) << 16);
            *(uint2*)&uL[Lr][64 + c4] = packed;
        }
    }
    __syncthreads();

    // ---- compute: thread (ty,tx) owns outputs i = i0 + ty*4 + r, j = tx*8 + v ----
    const int ty = tid >> 4, tx = tid & 15;

    float acc[4][8];
#pragma unroll
    for (int r = 0; r < 4; ++r)
#pragma unroll
        for (int v = 0; v < 8; ++v) acc[r][v] = 0.f;

#pragma unroll 1
    for (int p = 0; p < 64; ++p) {
        const int R0 = ty*4 + 63 - p;          // LDS row of (i - p) for r = 0
#pragma unroll
        for (int qc = 0; qc < 8; ++qc) {       // q = qc*8 + qq
            const int cb = (tx - qc)*8 + 56;   // window start col, in [0, 176], 8-granular
            const float4 ka = *(const float4*)&kL[p][qc*8];
            const float4 kb = *(const float4*)&kL[p][qc*8 + 4];
            const float kf[8] = {ka.x, ka.y, ka.z, ka.w, kb.x, kb.y, kb.z, kb.w};

            float uf[4][16];                   // uf[r][x] = uL[R0+r][cb+x] as f32
#pragma unroll
            for (int r = 0; r < 4; ++r) {
                const uint4 w0 = *(const uint4*)&uL[R0 + r][cb];
                const uint4 w1 = *(const uint4*)&uL[R0 + r][cb + 8];
                const uint32 ws[8] = {w0.x, w0.y, w0.z, w0.w, w1.x, w1.y, w1.z, w1.w};
#pragma unroll
                for (int e = 0; e < 8; ++e) {
                    uf[r][e*2]     = __uint_as_float(ws[e] << 16);
                    uf[r][e*2 + 1] = __uint_as_float(ws[e] & 0xffff0000u);
                }
            }
            // col = cb + (8 + v - qq)  ==  LDS col of (j - q); index in [1,15]
#pragma unroll
            for (int qq = 0; qq < 8; ++qq)
#pragma unroll
                for (int r = 0; r < 4; ++r)
#pragma unroll
                    for (int v = 0; v < 8; ++v)
                        acc[r][v] += uf[r][8 + v - qq] * kf[qq];
        }
    }

    // ---- epilogue: y * postgate, coalesced float4 stores ----
#pragma unroll
    for (int r = 0; r < 4; ++r) {
        const int i = i0 + ty*4 + r;
        float*       orow = oimg + i*128 + tx*8;
        const float* grow = gimg + i*128 + tx*8;
        float4 g0 = *(const float4*)grow;
        float4 g1 = *(const float4*)(grow + 4);
        float4 o0 = make_float4(acc[r][0]*g0.x, acc[r][1]*g0.y, acc[r][2]*g0.z, acc[r][3]*g0.w);
        float4 o1 = make_float4(acc[r][4]*g1.x, acc[r][5]*g1.y, acc[r][6]*g1.z, acc[r][7]*g1.w);
        *(float4*)orow       = o0;
        *(float4*)(orow + 4) = o1;
    }
}

extern "C" void kernel_launch(void* const* d_in, const int* in_sizes, int n_in,
                              void* d_out, int out_size, void* d_ws, size_t ws_size,
                              hipStream_t stream) {
    const float* u    = (const float*)d_in[0];  // (4,256,128,128)
    const float* k    = (const float*)d_in[1];  // (256,64,64)
    const float* pre  = (const float*)d_in[2];  // (4,256,128,128)
    const float* post = (const float*)d_in[3];  // (4,256,128,128)
    float* out = (float*)d_out;                 // (4,256,128,128) fp32

    // one workgroup per (image, row-half): 4*256*2 = 2048 blocks, 256 threads
    conv_direct<<<dim3(2048), dim3(256), 0, stream>>>(u, k, pre, post, out);
}

// Round 2
// 1947.132 us; speedup vs baseline: 1.0374x; 1.0374x over previous
//
#include <hip/hip_runtime.h>

// FlashFFTConvND == depthwise linear 2D conv (circular 256-pad == linear since
// 128+64-1 <= 256):  y[i][j] = postgate * sum_{r,q} x[r][j-q] * k[i-r][q],
// x = u*pregate zero-padded, r,q reductions done on the MFMA pipe.
//
// R2: MFMA 16x16x32 bf16. D[m][n]: m -> j (output col), n -> i (output row).
//   A[m][kk] = x[r][j - (q0+kk)]   (Hankel; xls stored column-REVERSED so the
//                                   8 k-elements per lane are contiguous)
//   B[kk][n] = kpad[15 + i - r][q0+kk]  (zero-padded kernel rows, clean reads)
// Per image: 7616 MFMAs (r-window clamped per 16-row i-tile). K-loop has no
// barriers; x/k staged once. Epilogue transposes acc through LDS for coalesced
// postgate*store.
// A-frag LDS addresses are 2B-granular per lane -> loaded via memcpy; compiler
// picks ds_read_b128-unaligned (fast) or ds_read_u16x8 (slow, still correct).
// R3 fallback if slow: stride-2-m parity pairs with ds_read2_b32.

typedef unsigned int uint32;
typedef short short8 __attribute__((ext_vector_type(8)));
typedef float float4v __attribute__((ext_vector_type(4)));

__device__ __forceinline__ unsigned short f2bf(float f) {
    uint32 x = __float_as_uint(f);
    uint32 r = (x + 0x7fffu + ((x >> 16) & 1u)) >> 16;
    return (unsigned short)r;
}

#define XLS_BYTES (128 * 192 * 2)          // 49152
#define KPAD_BYTES (94 * 72 * 2)           // 13536
#define SMEM_BYTES (XLS_BYTES + KPAD_BYTES) // 62688 (< 64K default limit)

__global__ __launch_bounds__(256, 2)
void conv_mfma(const float* __restrict__ u, const float* __restrict__ kk,
               const float* __restrict__ pregate, const float* __restrict__ postgate,
               float* __restrict__ out)
{
    extern __shared__ char smem[];
    // xls[r][c] = x[r][127 - c], c in [0,192); c in [128,191] is the zero halo
    // (x cols < 0). Row pitch 384B (16B-aligned rows).
    unsigned short (*xls)[192]  = (unsigned short(*)[192])smem;
    // kpad[p+15][q], rows p in [-15,78] (zeros outside p in [0,64)), pitch
    // 144B = 36 dwords -> bank stride 4 per row = conflict-floor reads.
    unsigned short (*kpad)[72]  = (unsigned short(*)[72])(smem + XLS_BYTES);

    const int img = blockIdx.x;            // b*256 + c
    const int c   = img & 255;
    const int tid = threadIdx.x;

    const float* uimg = u        + (size_t)img * (128*128);
    const float* pimg = pregate  + (size_t)img * (128*128);
    const float* gimg = postgate + (size_t)img * (128*128);
    float*       oimg = out      + (size_t)img * (128*128);
    const float* kimg = kk       + (size_t)c   * (64*64);

    // ---- stage: kpad zero-fill (flat 846 uint4) ----
    {
        uint4 z = make_uint4(0u,0u,0u,0u);
        uint4* kp4 = (uint4*)&kpad[0][0];
        for (int t = tid; t < KPAD_BYTES/16; t += 256) kp4[t] = z;
    }
    // ---- stage: xls zero halo, cols [128,192) of every row ----
    {
        uint4 z = make_uint4(0u,0u,0u,0u);
        for (int t = tid; t < 128*8; t += 256) {
            int r = t >> 3, c8 = 128 + ((t & 7) << 3);
            *(uint4*)&xls[r][c8] = z;
        }
    }
    // ---- stage: xls values, reversed: xls[r][120-c8+d] = x[r][c8+7-d] ----
    for (int t = tid; t < 128*16; t += 256) {
        int r = t >> 4, c8 = (t & 15) << 3;
        const float4 u0 = *(const float4*)(uimg + r*128 + c8);
        const float4 u1 = *(const float4*)(uimg + r*128 + c8 + 4);
        const float4 p0 = *(const float4*)(pimg + r*128 + c8);
        const float4 p1 = *(const float4*)(pimg + r*128 + c8 + 4);
        unsigned short h0 = f2bf(u0.x*p0.x), h1 = f2bf(u0.y*p0.y);
        unsigned short h2 = f2bf(u0.z*p0.z), h3 = f2bf(u0.w*p0.w);
        unsigned short h4 = f2bf(u1.x*p1.x), h5 = f2bf(u1.y*p1.y);
        unsigned short h6 = f2bf(u1.z*p1.z), h7 = f2bf(u1.w*p1.w);
        uint4 w;                                   // reversed order
        w.x = (uint32)h7 | ((uint32)h6 << 16);
        w.y = (uint32)h5 | ((uint32)h4 << 16);
        w.z = (uint32)h3 | ((uint32)h2 << 16);
        w.w = (uint32)h1 | ((uint32)h0 << 16);
        *(uint4*)&xls[r][120 - c8] = w;
    }
    // ---- stage: kpad values, rows [15,79) = k rows [0,64) ----
    for (int t = tid; t < 64*16; t += 256) {
        int p = t >> 4, c4 = (t & 15) << 2;
        const float4 kv = *(const float4*)(kimg + p*64 + c4);
        uint2 w;
        w.x = (uint32)f2bf(kv.x) | ((uint32)f2bf(kv.y) << 16);
        w.y = (uint32)f2bf(kv.z) | ((uint32)f2bf(kv.w) << 16);
        *(uint2*)&kpad[15 + p][c4] = w;
    }
    __syncthreads();

    // ---- K-loop: wave (jh,ih) owns j in [64jh,+64) x i in [64ih,+64) ----
    const int wv   = tid >> 6;
    const int lane = tid & 63;
    const int jh = wv & 1, ih = wv >> 1;
    const int J0 = jh << 6, I0 = ih << 6;
    const int m    = lane & 15;          // A's m / B's n / D's col-lane
    const int quad = lane >> 4;

    float4v acc[4][4] = {};              // [mt][nt], 64 VGPRs

    const int rlo = (I0 - 63 > 0) ? I0 - 63 : 0;
    const int rhi = (I0 + 63 < 127) ? I0 + 63 : 127;
    // cA is r-invariant; only the xls row advances.
    int cA0[4];
#pragma unroll
    for (int mt = 0; mt < 4; ++mt) cA0[mt] = 127 - J0 - 16*mt - m + 8*quad;

#pragma unroll 1
    for (int r = rlo; r <= rhi; ++r) {
        int ntlo = (r - I0) >> 4; if (ntlo < 0) ntlo = 0;
        int nthi = (r + 63 - I0) >> 4; if (nthi > 3) nthi = 3;
#pragma unroll
        for (int q0 = 0; q0 < 64; q0 += 32) {
            short8 av[4];
#pragma unroll
            for (int mt = 0; mt < 4; ++mt) {
                // per-lane 2B-granular Hankel read; memcpy keeps it legal
                __builtin_memcpy(&av[mt], &xls[r][cA0[mt] + q0], 16);
            }
#pragma unroll 1
            for (int nt = ntlo; nt <= nthi; ++nt) {
                const int p15 = 15 + I0 + 16*nt + m - r;
                short8 bv = *(const short8*)&kpad[p15][q0 + 8*quad];
                acc[0][nt] = __builtin_amdgcn_mfma_f32_16x16x32_bf16(av[0], bv, acc[0][nt], 0,0,0);
                acc[1][nt] = __builtin_amdgcn_mfma_f32_16x16x32_bf16(av[1], bv, acc[1][nt], 0,0,0);
                acc[2][nt] = __builtin_amdgcn_mfma_f32_16x16x32_bf16(av[2], bv, acc[2][nt], 0,0,0);
                acc[3][nt] = __builtin_amdgcn_mfma_f32_16x16x32_bf16(av[3], bv, acc[3][nt], 0,0,0);
            }
        }
    }

    // ---- epilogue: acc -> LDS transpose -> postgate * store (two phases) ----
    __syncthreads();
    float (*bufE)[132] = (float(*)[132])smem;   // 64x132 fp32 = 33 KiB, reuses xls
    for (int h = 0; h < 2; ++h) {
        if (ih == h) {
#pragma unroll
            for (int mt = 0; mt < 4; ++mt)
#pragma unroll
                for (int nt = 0; nt < 4; ++nt)
#pragma unroll
                    for (int rg = 0; rg < 4; ++rg) {
                        int iloc = 16*nt + m;               // i - 64h
                        int j    = J0 + 16*mt + 4*quad + rg; // D row = 4*quad+reg -> j
                        bufE[iloc][j] = acc[mt][nt][rg];
                    }
        }
        __syncthreads();
#pragma unroll 1
        for (int s = 0; s < 8; ++s) {
            int chunk = (s << 8) + tid;          // 2048 float4 chunks
            int row = chunk >> 5, c4 = (chunk & 31) << 2;
            float4 v = *(float4*)&bufE[row][c4];
            int gi = (h << 6) + row;
            const float4 g = *(const float4*)(gimg + gi*128 + c4);
            float4 o;
            o.x = v.x*g.x; o.y = v.y*g.y; o.z = v.z*g.z; o.w = v.w*g.w;
            *(float4*)(oimg + gi*128 + c4) = o;
        }
        __syncthreads();
    }
}

extern "C" void kernel_launch(void* const* d_in, const int* in_sizes, int n_in,
                              void* d_out, int out_size, void* d_ws, size_t ws_size,
                              hipStream_t stream) {
    const float* u    = (const float*)d_in[0];  // (4,256,128,128)
    const float* k    = (const float*)d_in[1];  // (256,64,64)
    const float* pre  = (const float*)d_in[2];  // (4,256,128,128)
    const float* post = (const float*)d_in[3];  // (4,256,128,128)
    float* out = (float*)d_out;                 // (4,256,128,128) fp32

    conv_mfma<<<dim3(1024), dim3(256), SMEM_BYTES, stream>>>(u, k, pre, post, out);
}

// Round 3
// 360.359 us; speedup vs baseline: 5.6054x; 5.4033x over previous
//
#include <hip/hip_runtime.h>

// FlashFFTConvND == depthwise linear 2D conv (circular 256-pad == linear since
// 128+64-1 <= 256):  y[i][j] = postgate * sum_{r,q} x[r][j-q] * k[i-r][q].
//
// R3: fix R2's accumulator spill (VGPR_Count=32, 3.8GB scratch writes) by
// full-unrolling nt with the out-of-window MFMAs absorbed by clamping the
// kpad row index into guaranteed-zero pad rows (acc indices all static).
// A-frags (Hankel) read deterministically: per lane, the 8 frags/row dedup to
// 6 windows (s=3-mt+2*q1), each = 5 dword-aligned LDS dwords + v_alignbit
// (shift 0/16 per lane). B-frags stay aligned ds_read_b128 from kpad.
// ih swizzled by (blockIdx>>8)&1 to balance the 64- vs 127-iter waves per SIMD.

typedef unsigned int uint32;
typedef short short8 __attribute__((ext_vector_type(8)));
typedef float float4v __attribute__((ext_vector_type(4)));
typedef uint32 uint4v __attribute__((ext_vector_type(4)));

__device__ __forceinline__ unsigned short f2bf(float f) {
    uint32 x = __float_as_uint(f);
    uint32 r = (x + 0x7fffu + ((x >> 16) & 1u)) >> 16;
    return (unsigned short)r;
}

#define XLS_BYTES (128 * 192 * 2)           // 49152
#define KPAD_BYTES (94 * 72 * 2)            // 13536
#define SMEM_BYTES (XLS_BYTES + KPAD_BYTES) // 62688 -> 2 blocks/CU

__global__ __launch_bounds__(256, 2)
void conv_mfma3(const float* __restrict__ u, const float* __restrict__ kk,
                const float* __restrict__ pregate, const float* __restrict__ postgate,
                float* __restrict__ out)
{
    extern __shared__ char smem[];
    // xls[r][c] = x[r][127 - c]; cols [128,192) = zero halo. Pitch 384B.
    unsigned short (*xls)[192]  = (unsigned short(*)[192])smem;
    // kpad[p+15][q]: rows 0..14 and 79..93 stay zero (clamp targets). Pitch 144B.
    unsigned short (*kpad)[72]  = (unsigned short(*)[72])(smem + XLS_BYTES);

    const int img = blockIdx.x;            // b*256 + c
    const int c   = img & 255;
    const int tid = threadIdx.x;

    const float* uimg = u        + (size_t)img * (128*128);
    const float* pimg = pregate  + (size_t)img * (128*128);
    const float* gimg = postgate + (size_t)img * (128*128);
    float*       oimg = out      + (size_t)img * (128*128);
    const float* kimg = kk       + (size_t)c   * (64*64);

    // ---- stage: kpad zero-fill ----
    {
        uint4 z = make_uint4(0u,0u,0u,0u);
        uint4* kp4 = (uint4*)&kpad[0][0];
        for (int t = tid; t < KPAD_BYTES/16; t += 256) kp4[t] = z;
    }
    // ---- stage: xls zero halo, cols [128,192) ----
    {
        uint4 z = make_uint4(0u,0u,0u,0u);
        for (int t = tid; t < 128*8; t += 256) {
            int r = t >> 3, c8 = 128 + ((t & 7) << 3);
            *(uint4*)&xls[r][c8] = z;
        }
    }
    // ---- stage: xls values (reversed): xls[r][120-c8+d] = x[r][c8+7-d] ----
    for (int t = tid; t < 128*16; t += 256) {
        int r = t >> 4, c8 = (t & 15) << 3;
        const float4 u0 = *(const float4*)(uimg + r*128 + c8);
        const float4 u1 = *(const float4*)(uimg + r*128 + c8 + 4);
        const float4 p0 = *(const float4*)(pimg + r*128 + c8);
        const float4 p1 = *(const float4*)(pimg + r*128 + c8 + 4);
        unsigned short h0 = f2bf(u0.x*p0.x), h1 = f2bf(u0.y*p0.y);
        unsigned short h2 = f2bf(u0.z*p0.z), h3 = f2bf(u0.w*p0.w);
        unsigned short h4 = f2bf(u1.x*p1.x), h5 = f2bf(u1.y*p1.y);
        unsigned short h6 = f2bf(u1.z*p1.z), h7 = f2bf(u1.w*p1.w);
        uint4 w;
        w.x = (uint32)h7 | ((uint32)h6 << 16);
        w.y = (uint32)h5 | ((uint32)h4 << 16);
        w.z = (uint32)h3 | ((uint32)h2 << 16);
        w.w = (uint32)h1 | ((uint32)h0 << 16);
        *(uint4*)&xls[r][120 - c8] = w;
    }
    // ---- stage: kpad rows [15,79) = k rows [0,64) ----
    for (int t = tid; t < 64*16; t += 256) {
        int p = t >> 4, c4 = (t & 15) << 2;
        const float4 kv = *(const float4*)(kimg + p*64 + c4);
        uint2 w;
        w.x = (uint32)f2bf(kv.x) | ((uint32)f2bf(kv.y) << 16);
        w.y = (uint32)f2bf(kv.z) | ((uint32)f2bf(kv.w) << 16);
        *(uint2*)&kpad[15 + p][c4] = w;
    }
    __syncthreads();

    // ---- K-loop ----
    const int wv   = tid >> 6;
    const int lane = tid & 63;
    const int jh = wv & 1;
    const int ih = ((wv >> 1) ^ ((blockIdx.x >> 8) & 1)) & 1;  // SIMD balance
    const int J0 = jh << 6, I0 = ih << 6;
    const int m    = lane & 15;
    const int quad = lane >> 4;

    float4v acc[4][4] = {};                // [mt][nt], static indices only

    const int rlo = (I0 - 63 > 0) ? I0 - 63 : 0;
    const int rhi = (I0 + 63 < 127) ? I0 + 63 : 127;

    // frag window s covers elems cd = cbase-48+16s .. +8 (s = 3-mt+2*q1)
    const int cbase = 127 - J0 - m + 8*quad;
    const uint32 sh = (uint32)((cbase & 1) << 4);    // alignbit shift: 0 or 16
    const int dws0  = (cbase - 48) >> 1;             // dword index of s=0 window

    const uint32* xls32 = (const uint32*)smem;       // xls as dwords, 96/row

#pragma unroll 1
    for (int r = rlo; r <= rhi; ++r) {
        const uint32* row32 = xls32 + r*96 + dws0;
        uint32 dw[6][5];
#pragma unroll
        for (int s = 0; s < 6; ++s) {
            const uint32* p = row32 + 8*s;
            dw[s][0] = p[0]; dw[s][1] = p[1]; dw[s][2] = p[2];
            dw[s][3] = p[3]; dw[s][4] = p[4];
        }
        short8 av[6];
#pragma unroll
        for (int s = 0; s < 6; ++s) {
            uint4v f;
            f.x = __builtin_amdgcn_alignbit(dw[s][1], dw[s][0], sh);
            f.y = __builtin_amdgcn_alignbit(dw[s][2], dw[s][1], sh);
            f.z = __builtin_amdgcn_alignbit(dw[s][3], dw[s][2], sh);
            f.w = __builtin_amdgcn_alignbit(dw[s][4], dw[s][3], sh);
            av[s] = __builtin_bit_cast(short8, f);
        }

        const int t0 = 15 + I0 + m - r;
#pragma unroll
        for (int q1 = 0; q1 < 2; ++q1) {
#pragma unroll
            for (int nt = 0; nt < 4; ++nt) {
                int p15 = t0 + 16*nt;
                p15 = p15 < 0 ? 0 : (p15 > 93 ? 93 : p15);   // zero pad rows
                const short8 bv = *(const short8*)&kpad[p15][32*q1 + 8*quad];
                acc[0][nt] = __builtin_amdgcn_mfma_f32_16x16x32_bf16(av[3 + 2*q1], bv, acc[0][nt], 0,0,0);
                acc[1][nt] = __builtin_amdgcn_mfma_f32_16x16x32_bf16(av[2 + 2*q1], bv, acc[1][nt], 0,0,0);
                acc[2][nt] = __builtin_amdgcn_mfma_f32_16x16x32_bf16(av[1 + 2*q1], bv, acc[2][nt], 0,0,0);
                acc[3][nt] = __builtin_amdgcn_mfma_f32_16x16x32_bf16(av[0 + 2*q1], bv, acc[3][nt], 0,0,0);
            }
        }
    }

    // ---- epilogue: acc -> LDS transpose -> postgate * store ----
    __syncthreads();
    float (*bufE)[132] = (float(*)[132])smem;   // 64x132 fp32 = 33 KiB
    for (int h = 0; h < 2; ++h) {
        if (ih == h) {
#pragma unroll
            for (int mt = 0; mt < 4; ++mt)
#pragma unroll
                for (int nt = 0; nt < 4; ++nt)
#pragma unroll
                    for (int rg = 0; rg < 4; ++rg) {
                        int iloc = 16*nt + m;                 // i - 64h
                        int j    = J0 + 16*mt + 4*quad + rg;  // D row -> j
                        bufE[iloc][j] = acc[mt][nt][rg];
                    }
        }
        __syncthreads();
#pragma unroll 1
        for (int s = 0; s < 8; ++s) {
            int chunk = (s << 8) + tid;
            int row = chunk >> 5, c4 = (chunk & 31) << 2;
            float4 v = *(float4*)&bufE[row][c4];
            int gi = (h << 6) + row;
            const float4 g = *(const float4*)(gimg + gi*128 + c4);
            float4 o;
            o.x = v.x*g.x; o.y = v.y*g.y; o.z = v.z*g.z; o.w = v.w*g.w;
            *(float4*)(oimg + gi*128 + c4) = o;
        }
        __syncthreads();
    }
}

extern "C" void kernel_launch(void* const* d_in, const int* in_sizes, int n_in,
                              void* d_out, int out_size, void* d_ws, size_t ws_size,
                              hipStream_t stream) {
    const float* u    = (const float*)d_in[0];  // (4,256,128,128)
    const float* k    = (const float*)d_in[1];  // (256,64,64)
    const float* pre  = (const float*)d_in[2];  // (4,256,128,128)
    const float* post = (const float*)d_in[3];  // (4,256,128,128)
    float* out = (float*)d_out;                 // (4,256,128,128) fp32

    conv_mfma3<<<dim3(1024), dim3(256), SMEM_BYTES, stream>>>(u, k, pre, post, out);
}